// Round 3
// baseline (283.049 us; speedup 1.0000x reference)
//
#include <hip/hip_runtime.h>
#include <hip/hip_bf16.h>

#define B_   8
#define LQ_  2048
#define LK_  2048
#define D_   128
#define QBLK 64
#define KBLK 64
#define KSPLIT 2
#define KRANGE (LK_ / KSPLIT)      // 1024 keys per block
#define NT    (KRANGE / KBLK)      // 16 key tiles per block
#define THREADS 512
#define SCALE 0.08838834764831845f // 1/sqrt(128)

typedef __attribute__((ext_vector_type(8))) __bf16 bf16x8;   // MFMA A/B frag (4 VGPRs)
typedef __attribute__((ext_vector_type(4))) __bf16 bf16x4;   // 8B LDS write
typedef __attribute__((ext_vector_type(4))) float  f32x4;    // MFMA C/D frag
typedef __attribute__((ext_vector_type(4))) float  fx4;      // global float4 load

// LDS layout (__bf16 units). Unpadded power-of-2 strides + G4 XOR swizzle
// (col ^= (row&7)<<3, elem units) => conflict-free 16-row ds_read_b128.
#define KS_OFF 0          // [64][128]   K tile (swizzled)
#define VT_OFF 8192       // [128][64]   V tile transposed Vt[d][k] (swizzled)
#define PS_OFF 16384      // 8 waves x [16][40] per-wave P tile
#define SMEM_ELEMS 21504  // 43008 B

__global__ __launch_bounds__(THREADS, 4)
void sigattn_kernel(const float* __restrict__ q, const float* __restrict__ k,
                    const float* __restrict__ v, const int* __restrict__ mask,
                    float* __restrict__ out)
{
    __shared__ __bf16 smem[SMEM_ELEMS];

    const int tid  = threadIdx.x;
    const int lane = tid & 63;
    const int wid  = tid >> 6;      // 0..7
    const int qg   = wid & 3;       // q-group: rows [qg*16, qg*16+16)
    const int kg   = wid >> 2;      // key-half: keys [kg*32, kg*32+32) of tile
    const int l15  = lane & 15;
    const int g    = lane >> 4;     // 0..3

    // bid%8 -> batch (XCD-local K/V/mask reuse in each XCD's L2);
    // bid>>3 -> (q-tile, key-split)
    const int bid  = blockIdx.x;
    const int b    = bid & 7;
    const int rest = bid >> 3;          // 0..63
    const int q0   = (rest >> 1) * QBLK;
    const int ks   = rest & 1;

    const float* qb = q + (size_t)b * LQ_ * D_ + (size_t)q0 * D_;
    const float* kb = k + (size_t)b * LK_ * D_ + (size_t)ks * KRANGE * D_;
    const float* vb = v + (size_t)b * LK_ * D_ + (size_t)ks * KRANGE * D_;
    const int*   mb = mask + (size_t)b * LQ_ * LK_ + (size_t)q0 * LK_ + (size_t)ks * KRANGE;
    float*       ob = out + (size_t)b * LQ_ * D_ + (size_t)q0 * D_;

    __bf16* Ks = smem + KS_OFF;
    __bf16* Vt = smem + VT_OFF;
    __bf16* Ps = smem + PS_OFF + wid * 640;   // private [16][40]

    const int dv  = tid & 127;   // V-transpose: this thread's d column
    const int kq8 = tid >> 7;    // 0..3 -> key-quad group
    const int vswz = ((dv & 7) << 3);   // Vt row swizzle

    int mcur[8];

    // ---------------- prologue ----------------
    // Q fragments straight from global (one-time): A[i=l15][d: dblk*32+g*8..+7]
    bf16x8 qfrag[4];
    {
        const float* qrow = qb + (qg * 16 + l15) * D_;
#pragma unroll
        for (int dblk = 0; dblk < 4; ++dblk) {
            fx4 f0 = *(const fx4*)(qrow + dblk * 32 + g * 8);
            fx4 f1 = *(const fx4*)(qrow + dblk * 32 + g * 8 + 4);
            bf16x8 w;
#pragma unroll
            for (int j = 0; j < 4; ++j) { w[j] = (__bf16)f0[j]; w[4 + j] = (__bf16)f1[j]; }
            qfrag[dblk] = w;
        }
    }
#pragma unroll
    for (int i = 0; i < 4; ++i) {               // K tile 0 (swizzled store)
        int idx = tid + i * THREADS;
        int row = idx >> 5, c4 = idx & 31;
        fx4 f = *(const fx4*)(kb + row * D_ + c4 * 4);
        bf16x4 w; w[0]=(__bf16)f[0]; w[1]=(__bf16)f[1]; w[2]=(__bf16)f[2]; w[3]=(__bf16)f[3];
        *(bf16x4*)(Ks + row * 128 + ((c4 * 4) ^ ((row & 7) << 3))) = w;
    }
#pragma unroll
    for (int i = 0; i < 4; ++i) {               // V tile 0 (transposed, swizzled)
        int quad = kq8 + i * 4;
        bf16x4 w;
#pragma unroll
        for (int j = 0; j < 4; ++j) w[j] = (__bf16)vb[(quad * 4 + j) * D_ + dv];
        *(bf16x4*)(Vt + dv * 64 + ((quad * 4) ^ vswz)) = w;
    }
#pragma unroll
    for (int n2 = 0; n2 < 2; ++n2)              // mask tile 0 -> regs (C/D order)
#pragma unroll
        for (int r = 0; r < 4; ++r)
            mcur[n2 * 4 + r] = mb[(qg * 16 + 4 * g + r) * LK_ + (kg * 32 + n2 * 16 + l15)];

    f32x4 oacc[8];
#pragma unroll
    for (int nb = 0; nb < 8; ++nb) oacc[nb] = (f32x4){0.f, 0.f, 0.f, 0.f};

    __syncthreads();

    // ---------------- main loop over key tiles ----------------
    for (int t = 0; t < NT; ++t) {
        const bool more = (t + 1 < NT);

        // prefetch tile t+1 into registers (latency hidden under compute)
        fx4   kreg[4];
        float vreg[16];
        int   mnxt[8];
        if (more) {
            const int kt = (t + 1) * KBLK;
#pragma unroll
            for (int i = 0; i < 4; ++i) {
                int idx = tid + i * THREADS;
                int row = idx >> 5, c4 = idx & 31;
                kreg[i] = *(const fx4*)(kb + (kt + row) * D_ + c4 * 4);
            }
#pragma unroll
            for (int i = 0; i < 4; ++i) {
                int quad = kq8 + i * 4;
#pragma unroll
                for (int j = 0; j < 4; ++j)
                    vreg[i * 4 + j] = vb[(kt + quad * 4 + j) * D_ + dv];
            }
#pragma unroll
            for (int n2 = 0; n2 < 2; ++n2)
#pragma unroll
                for (int r = 0; r < 4; ++r)
                    mnxt[n2 * 4 + r] = mb[(qg * 16 + 4 * g + r) * LK_ + (kt + kg * 32 + n2 * 16 + l15)];
        }

        // ---- QK^T: S[q][key], wave covers 16 q x 32 keys ----
        f32x4 sacc[2];
        sacc[0] = (f32x4){0.f, 0.f, 0.f, 0.f};
        sacc[1] = (f32x4){0.f, 0.f, 0.f, 0.f};
#pragma unroll
        for (int n2 = 0; n2 < 2; ++n2) {
            const int krow = kg * 32 + n2 * 16 + l15;
            const __bf16* kbase = Ks + krow * 128;
            const int kswz = (krow & 7) << 3;
#pragma unroll
            for (int dblk = 0; dblk < 4; ++dblk) {
                bf16x8 bfr = *(const bf16x8*)(kbase + ((dblk * 32 + g * 8) ^ kswz));
                sacc[n2] = __builtin_amdgcn_mfma_f32_16x16x32_bf16(qfrag[dblk], bfr, sacc[n2], 0, 0, 0);
            }
        }

        // ---- mask + sigmoid -> P (bf16) into wave-private LDS ----
#pragma unroll
        for (int n2 = 0; n2 < 2; ++n2)
#pragma unroll
            for (int r = 0; r < 4; ++r) {
                float s = sacc[n2][r] * SCALE;
                float p = (mcur[n2 * 4 + r] != 0)
                            ? 0.0f
                            : __builtin_amdgcn_rcpf(1.0f + __expf(-s));
                Ps[(4 * g + r) * 40 + n2 * 16 + l15] = (__bf16)p;
            }

        // ---- PV: out += P(16x32) * V(32x128) ----
        bf16x8 pfrag = *(const bf16x8*)(Ps + l15 * 40 + g * 8);
#pragma unroll
        for (int nb = 0; nb < 8; ++nb) {
            const int vrow = nb * 16 + l15;
            bf16x8 vfr = *(const bf16x8*)(Vt + vrow * 64 + ((kg * 32 + g * 8) ^ ((vrow & 7) << 3)));
            oacc[nb] = __builtin_amdgcn_mfma_f32_16x16x32_bf16(pfrag, vfr, oacc[nb], 0, 0, 0);
        }

        __syncthreads();   // everyone done reading K/Vt of tile t

        // ---- write staged tile t+1 to LDS ----
        if (more) {
#pragma unroll
            for (int i = 0; i < 4; ++i) {
                int idx = tid + i * THREADS;
                int row = idx >> 5, c4 = idx & 31;
                bf16x4 w;
                w[0]=(__bf16)kreg[i][0]; w[1]=(__bf16)kreg[i][1];
                w[2]=(__bf16)kreg[i][2]; w[3]=(__bf16)kreg[i][3];
                *(bf16x4*)(Ks + row * 128 + ((c4 * 4) ^ ((row & 7) << 3))) = w;
            }
#pragma unroll
            for (int i = 0; i < 4; ++i) {
                int quad = kq8 + i * 4;
                bf16x4 w;
#pragma unroll
                for (int j = 0; j < 4; ++j) w[j] = (__bf16)vreg[i * 4 + j];
                *(bf16x4*)(Vt + dv * 64 + ((quad * 4) ^ vswz)) = w;
            }
#pragma unroll
            for (int j = 0; j < 8; ++j) mcur[j] = mnxt[j];
        }

        __syncthreads();   // tile t+1 visible before next compute
    }

    // ---------------- epilogue: reduce kg halves, atomicAdd to out ----------------
    float* red = (float*)smem;    // f32 [64][128] overlay (post-barrier safe)
    if (kg == 0) {
#pragma unroll
        for (int nb = 0; nb < 8; ++nb)
#pragma unroll
            for (int r = 0; r < 4; ++r)
                red[(qg * 16 + 4 * g + r) * 128 + nb * 16 + l15] = oacc[nb][r];
    }
    __syncthreads();
    if (kg == 1) {
#pragma unroll
        for (int nb = 0; nb < 8; ++nb)
#pragma unroll
            for (int r = 0; r < 4; ++r) {
                int row = qg * 16 + 4 * g + r;
                float val = red[row * 128 + nb * 16 + l15] + oacc[nb][r];
                atomicAdd(&ob[(size_t)row * D_ + nb * 16 + l15], val);
            }
    }
}

extern "C" void kernel_launch(void* const* d_in, const int* in_sizes, int n_in,
                              void* d_out, int out_size, void* d_ws, size_t ws_size,
                              hipStream_t stream) {
    const float* q    = (const float*)d_in[0];
    const float* k    = (const float*)d_in[1];
    const float* v    = (const float*)d_in[2];
    const int*   mask = (const int*)d_in[3];
    float*       out  = (float*)d_out;

    // zero out for the key-split atomic accumulation (capture-safe async memset)
    hipMemsetAsync(out, 0, (size_t)out_size * sizeof(float), stream);

    dim3 grid(B_ * (LQ_ / QBLK) * KSPLIT);   // 512 blocks
    dim3 block(THREADS);
    sigattn_kernel<<<grid, block, 0, stream>>>(q, k, v, mask, out);
}

// Round 4
// 246.668 us; speedup vs baseline: 1.1475x; 1.1475x over previous
//
#include <hip/hip_runtime.h>
#include <hip/hip_bf16.h>

#define B_   8
#define LQ_  2048
#define LK_  2048
#define D_   128
#define QBLK 64
#define KBLK 64
#define KSPLIT 2
#define KRANGE (LK_ / KSPLIT)      // 1024 keys per block
#define NT    (KRANGE / KBLK)      // 16 key tiles per block
#define THREADS 512
#define SCALE 0.08838834764831845f // 1/sqrt(128)

typedef __attribute__((ext_vector_type(8))) __bf16 bf16x8;   // MFMA A/B frag (4 VGPRs)
typedef __attribute__((ext_vector_type(4))) __bf16 bf16x4;   // 8B LDS r/w
typedef __attribute__((ext_vector_type(4))) float  f32x4;    // MFMA C/D frag
typedef __attribute__((ext_vector_type(4))) float  fx4;      // global float4 load
typedef __attribute__((ext_vector_type(2))) float  fx2;      // global float2 load

// LDS (__bf16 units):
//   Ks [64][128]  key-major K tile, 8-granular XOR swizzle  (16 KB)
//   Vt [128][64]  d-major V tile, SLOT-permuted keys, 4-granular XOR swizzle (16 KB)
// slot(s = g*8 + n2*4 + r) holds key n2*16 + 4*g + r  -> matches in-register
// P fragment k-ordering from the swapped QK^T (S^T) layout.
#define KS_OFF 0
#define VT_OFF 8192
#define SMEM_ELEMS 16384   // 32 KB; epilogue overlays f32 [64][128] = 32 KB

__global__ __launch_bounds__(THREADS, 4)
void sigattn_kernel(const float* __restrict__ q, const float* __restrict__ k,
                    const float* __restrict__ v, const int* __restrict__ mask,
                    float* __restrict__ out, float* __restrict__ ws)
{
    __shared__ __bf16 smem[SMEM_ELEMS];

    const int tid  = threadIdx.x;
    const int lane = tid & 63;
    const int wid  = tid >> 6;      // 0..7
    const int qg   = wid & 3;       // q-group: rows [qg*16, qg*16+16)
    const int kg   = wid >> 2;      // key-half: keys [kg*32, kg*32+32) of tile
    const int l15  = lane & 15;
    const int g    = lane >> 4;     // 0..3

    const int bid  = blockIdx.x;
    const int b    = bid & 7;           // batch -> XCD-local L2 reuse
    const int rest = bid >> 3;          // 0..63
    const int q0   = (rest >> 1) * QBLK;
    const int ks   = rest & 1;

    const float* qb = q + (size_t)b * LQ_ * D_ + (size_t)q0 * D_;
    const float* kb = k + (size_t)b * LK_ * D_ + (size_t)ks * KRANGE * D_;
    const float* vb = v + (size_t)b * LK_ * D_ + (size_t)ks * KRANGE * D_;
    const int*   mb = mask + (size_t)b * LQ_ * LK_ + (size_t)q0 * LK_ + (size_t)ks * KRANGE;
    float*       ob = out + (size_t)b * LQ_ * D_ + (size_t)q0 * D_;
    float*       wb = ws  + (size_t)b * LQ_ * D_ + (size_t)q0 * D_;

    __bf16* Ks = smem + KS_OFF;
    __bf16* Vt = smem + VT_OFF;

    // ---- V staging geometry: thread t handles d-pair dcol..dcol+1, keys kgrp*8..+7
    const int dcol  = (tid & 63) * 2;
    const int kgrp  = tid >> 6;                    // 0..7
    const int vswzq = (tid & 15) << 2;             // ((d>>1)&15)<<2, same for both dd
    const int colbase = ((kgrp >> 2) << 5) + ((kgrp & 1) << 4) + (((kgrp >> 1) & 1) << 2);
    const float* vbase = vb + (size_t)(kgrp * 8) * D_ + dcol;

    // ---- mask: coalesced source pattern + ballot redistribution
    const int* mbase_p = mb + (qg * 16 + 4 * g) * LK_ + kg * 32 + l15;
    const int  rsel   = lane & 3;
    const int  mshift = ((lane & 15) >> 2) * 16 + 4 * (lane >> 4);

    int mcur[8];

    // ---------------- prologue ----------------
    // Q fragments straight from global: lane holds Q[qg*16+l15][dblk*32+g*8 .. +7]
    bf16x8 qfrag[4];
    {
        const float* qrow = qb + (qg * 16 + l15) * D_;
#pragma unroll
        for (int dblk = 0; dblk < 4; ++dblk) {
            fx4 f0 = *(const fx4*)(qrow + dblk * 32 + g * 8);
            fx4 f1 = *(const fx4*)(qrow + dblk * 32 + g * 8 + 4);
            bf16x8 w;
#pragma unroll
            for (int j = 0; j < 4; ++j) { w[j] = (__bf16)f0[j]; w[4 + j] = (__bf16)f1[j]; }
            qfrag[dblk] = w;
        }
    }
#pragma unroll
    for (int i = 0; i < 4; ++i) {               // K tile 0 (swizzled store)
        int idx = tid + i * THREADS;
        int row = idx >> 5, c4 = idx & 31;
        fx4 f = *(const fx4*)(kb + row * D_ + c4 * 4);
        bf16x4 w; w[0]=(__bf16)f[0]; w[1]=(__bf16)f[1]; w[2]=(__bf16)f[2]; w[3]=(__bf16)f[3];
        *(bf16x4*)(Ks + row * 128 + ((c4 * 4) ^ ((row & 7) << 3))) = w;
    }
    {                                           // V tile 0 (slot-permuted, swizzled)
        fx2 vld[8];
#pragma unroll
        for (int j = 0; j < 8; ++j) vld[j] = *(const fx2*)(vbase + j * D_);
#pragma unroll
        for (int dd = 0; dd < 2; ++dd) {
            bf16x4 lo, hi;
#pragma unroll
            for (int j = 0; j < 4; ++j) { lo[j] = (__bf16)vld[j][dd]; hi[j] = (__bf16)vld[4 + j][dd]; }
            __bf16* vr = Vt + (dcol + dd) * 64;
            *(bf16x4*)(vr + (colbase ^ vswzq)) = lo;
            *(bf16x4*)(vr + ((colbase + 8) ^ vswzq)) = hi;
        }
    }
#pragma unroll
    for (int n2 = 0; n2 < 2; ++n2)              // mask tile 0 (coalesced)
#pragma unroll
        for (int r = 0; r < 4; ++r)
            mcur[n2 * 4 + r] = mbase_p[r * LK_ + n2 * 16];

    f32x4 oacc[8];
#pragma unroll
    for (int nb = 0; nb < 8; ++nb) oacc[nb] = (f32x4){0.f, 0.f, 0.f, 0.f};

    __syncthreads();

    // ---------------- main loop over key tiles ----------------
    for (int t = 0; t < NT; ++t) {
        const bool more = (t + 1 < NT);

        // prefetch tile t+1 into registers
        fx4 kreg[4];
        fx2 vld[8];
        int mnxt[8];
        if (more) {
            const int kt = (t + 1) * KBLK;
#pragma unroll
            for (int i = 0; i < 4; ++i) {
                int idx = tid + i * THREADS;
                int row = idx >> 5, c4 = idx & 31;
                kreg[i] = *(const fx4*)(kb + (kt + row) * D_ + c4 * 4);
            }
#pragma unroll
            for (int j = 0; j < 8; ++j) vld[j] = *(const fx2*)(vbase + (kt + j) * D_);
#pragma unroll
            for (int n2 = 0; n2 < 2; ++n2)
#pragma unroll
                for (int r = 0; r < 4; ++r)
                    mnxt[n2 * 4 + r] = mbase_p[r * LK_ + kt + n2 * 16];
        }

        // ---- QK^T swapped: S^T = mfma(K, Q); lane: q = l15, key = kg*32+n2*16+4g+r
        f32x4 sacc[2];
        sacc[0] = (f32x4){0.f, 0.f, 0.f, 0.f};
        sacc[1] = (f32x4){0.f, 0.f, 0.f, 0.f};
#pragma unroll
        for (int n2 = 0; n2 < 2; ++n2) {
            const int krow = kg * 32 + n2 * 16 + l15;
            const __bf16* kbase = Ks + krow * 128;
            const int kswz = (krow & 7) << 3;
#pragma unroll
            for (int dblk = 0; dblk < 4; ++dblk) {
                bf16x8 kfr = *(const bf16x8*)(kbase + ((dblk * 32 + g * 8) ^ kswz));
                sacc[n2] = __builtin_amdgcn_mfma_f32_16x16x32_bf16(kfr, qfrag[dblk], sacc[n2], 0, 0, 0);
            }
        }

        // ---- ballots: redistribute mask bits to transposed consumers (no LDS)
        unsigned long long bl[8];
#pragma unroll
        for (int j = 0; j < 8; ++j) bl[j] = __ballot(mcur[j] != 0);
        unsigned long long bb0 = (rsel & 2) ? ((rsel & 1) ? bl[3] : bl[2])
                                            : ((rsel & 1) ? bl[1] : bl[0]);
        unsigned long long bb1 = (rsel & 2) ? ((rsel & 1) ? bl[7] : bl[6])
                                            : ((rsel & 1) ? bl[5] : bl[4]);
        const unsigned int bits0 = (unsigned int)(bb0 >> mshift) & 0xFu;
        const unsigned int bits1 = (unsigned int)(bb1 >> mshift) & 0xFu;

        // ---- sigmoid + mask, packed straight into the PV A-fragment
        bf16x8 pfrag;
#pragma unroll
        for (int n2 = 0; n2 < 2; ++n2) {
            const unsigned int bits = n2 ? bits1 : bits0;
#pragma unroll
            for (int r = 0; r < 4; ++r) {
                float s = sacc[n2][r] * SCALE;
                float p = __builtin_amdgcn_rcpf(1.0f + __expf(-s));
                p = ((bits >> r) & 1u) ? 0.0f : p;
                pfrag[n2 * 4 + r] = (__bf16)p;
            }
        }

        // ---- PV: oacc += P(16x32) * V(32x128), slot-permuted V, b64 reads
#pragma unroll
        for (int nb = 0; nb < 8; ++nb) {
            const int row = nb * 16 + l15;
            const int swz = ((nb & 1) << 5) | ((l15 >> 1) << 2);
            const __bf16* vrow = Vt + row * 64;
            const int c = kg * 32 + g * 8;
            bf16x4 v0 = *(const bf16x4*)(vrow + (c ^ swz));
            bf16x4 v1 = *(const bf16x4*)(vrow + ((c + 4) ^ swz));
            bf16x8 vfr;
#pragma unroll
            for (int j = 0; j < 4; ++j) { vfr[j] = v0[j]; vfr[4 + j] = v1[j]; }
            oacc[nb] = __builtin_amdgcn_mfma_f32_16x16x32_bf16(pfrag, vfr, oacc[nb], 0, 0, 0);
        }

        __syncthreads();   // done reading K/Vt of tile t

        // ---- write staged tile t+1 to LDS
        if (more) {
#pragma unroll
            for (int i = 0; i < 4; ++i) {
                int idx = tid + i * THREADS;
                int row = idx >> 5, c4 = idx & 31;
                bf16x4 w;
                w[0]=(__bf16)kreg[i][0]; w[1]=(__bf16)kreg[i][1];
                w[2]=(__bf16)kreg[i][2]; w[3]=(__bf16)kreg[i][3];
                *(bf16x4*)(Ks + row * 128 + ((c4 * 4) ^ ((row & 7) << 3))) = w;
            }
#pragma unroll
            for (int dd = 0; dd < 2; ++dd) {
                bf16x4 lo, hi;
#pragma unroll
                for (int j = 0; j < 4; ++j) { lo[j] = (__bf16)vld[j][dd]; hi[j] = (__bf16)vld[4 + j][dd]; }
                __bf16* vr = Vt + (dcol + dd) * 64;
                *(bf16x4*)(vr + (colbase ^ vswzq)) = lo;
                *(bf16x4*)(vr + ((colbase + 8) ^ vswzq)) = hi;
            }
#pragma unroll
            for (int j = 0; j < 8; ++j) mcur[j] = mnxt[j];
        }

        __syncthreads();   // tile t+1 visible
    }

    // ---------------- epilogue: reduce kg halves, plain stores ----------------
    float* red = (float*)smem;    // f32 [64][128] overlay (post-barrier safe)
    if (kg == 0) {
#pragma unroll
        for (int nb = 0; nb < 8; ++nb)
#pragma unroll
            for (int r = 0; r < 4; ++r)
                red[(qg * 16 + 4 * g + r) * 128 + nb * 16 + l15] = oacc[nb][r];
    }
    __syncthreads();
    if (kg == 1) {
        float* dst = ks ? wb : ob;
#pragma unroll
        for (int nb = 0; nb < 8; ++nb)
#pragma unroll
            for (int r = 0; r < 4; ++r) {
                int row = qg * 16 + 4 * g + r;
                dst[(size_t)row * D_ + nb * 16 + l15] =
                    red[row * 128 + nb * 16 + l15] + oacc[nb][r];
            }
    }
}

__global__ __launch_bounds__(256)
void reduce_add_kernel(float* __restrict__ out, const float* __restrict__ ws, int n4)
{
    int i = blockIdx.x * blockDim.x + threadIdx.x;
    if (i < n4) {
        fx4 a = *(const fx4*)(out + i * 4);
        fx4 c = *(const fx4*)(ws + i * 4);
        a[0]+=c[0]; a[1]+=c[1]; a[2]+=c[2]; a[3]+=c[3];
        *(fx4*)(out + i * 4) = a;
    }
}

extern "C" void kernel_launch(void* const* d_in, const int* in_sizes, int n_in,
                              void* d_out, int out_size, void* d_ws, size_t ws_size,
                              hipStream_t stream) {
    const float* q    = (const float*)d_in[0];
    const float* k    = (const float*)d_in[1];
    const float* v    = (const float*)d_in[2];
    const int*   mask = (const int*)d_in[3];
    float*       out  = (float*)d_out;
    float*       ws   = (float*)d_ws;      // 8 MB partials for the ks=1 half

    dim3 grid(B_ * (LQ_ / QBLK) * KSPLIT);   // 512 blocks -> 2 per CU
    sigattn_kernel<<<grid, dim3(THREADS), 0, stream>>>(q, k, v, mask, out, ws);

    const int n4 = out_size / 4;             // 524288 float4s
    reduce_add_kernel<<<(n4 + 255) / 256, 256, 0, stream>>>(out, ws, n4);
}